// Round 18
// baseline (279.573 us; speedup 1.0000x reference)
//
#include <hip/hip_runtime.h>
#include <hip/hip_bf16.h>
#include <cstdint>
#include <cmath>

#define DEV __device__ __forceinline__

typedef float f32x4 __attribute__((ext_vector_type(4)));
typedef float f32x16 __attribute__((ext_vector_type(16)));
typedef __bf16 bf16x8 __attribute__((ext_vector_type(8)));
typedef unsigned short u16;
typedef u16 u16x8 __attribute__((ext_vector_type(8)));
typedef u16 u16x4 __attribute__((ext_vector_type(4)));

DEV u16 f2bf(float f) {
  union { float f; uint32_t u; } x{f};
  uint32_t r = x.u + 0x7FFFu + ((x.u >> 16) & 1u);
  return (u16)(r >> 16);
}

DEV float b2f(u16 h) {
  union { uint32_t u; float f; } x{(uint32_t)h << 16};
  return x.f;
}

DEV void gl_lds16(const u16* g, u16* l) {
  __builtin_amdgcn_global_load_lds((const __attribute__((address_space(1))) void*)g,
                                   (__attribute__((address_space(3))) void*)l, 16, 0, 0);
}

// ---------------- fused f32 -> bf16 convert (all 7 tensors, one launch) ----
__global__ __launch_bounds__(256) void k_cvt_all(
    const float* __restrict__ emb, const float* __restrict__ Wq,
    const float* __restrict__ Wk, const float* __restrict__ Wv,
    const float* __restrict__ W0, const float* __restrict__ W1,
    const float* __restrict__ W2,
    u16* __restrict__ embb, u16* __restrict__ Wqb, u16* __restrict__ Wkb,
    u16* __restrict__ Wvb, u16* __restrict__ W0b, u16* __restrict__ W1b,
    u16* __restrict__ W2b) {
  const int step = gridDim.x * blockDim.x;
  for (int i4 = blockIdx.x * blockDim.x + threadIdx.x; i4 < 4194304; i4 += step) {
    const int i = i4 * 4;
    const float* s; u16* d; int off;
    if (i < 4194304)       { s = emb; d = embb; off = 0; }
    else if (i < 5242880)  { s = Wq;  d = Wqb;  off = 4194304; }
    else if (i < 6291456)  { s = Wk;  d = Wkb;  off = 5242880; }
    else if (i < 7340032)  { s = Wv;  d = Wvb;  off = 6291456; }
    else if (i < 8388608)  { s = W0;  d = W0b;  off = 7340032; }
    else if (i < 12582912) { s = W1;  d = W1b;  off = 8388608; }
    else                   { s = W2;  d = W2b;  off = 12582912; }
    float4 v = *reinterpret_cast<const float4*>(s + (i - off));
    u16x4 o;
    o[0] = f2bf(v.x); o[1] = f2bf(v.y); o[2] = f2bf(v.z); o[3] = f2bf(v.w);
    *reinterpret_cast<u16x4*>(d + (i - off)) = o;
  }
}

// ---------------- GEMM core: C[M,N] = A[M,K] @ B[N,K]^T ----------------
// 64x128 tile, 4 waves (2x2 of 32x64), BK=64 -> 16 MFMA per wave per K-step,
// LDS 48 KB, chunk-XOR swizzled on BOTH sides (bank-conflict-free b128 reads).
// MODE 0: bf16 out = (acc+bias)*oscale ; MODE 1: bf16 out = relu(acc+bias)
// MODE 3: f32 out = acc (raw partial) ; MODE 4: bf16 out = acc (raw partial)
template <int MODE>
DEV void gemm_core64(const u16* __restrict__ A, const u16* __restrict__ B,
                     const float* __restrict__ bias,
                     void* __restrict__ C, int N, int K, int KL,
                     int m0, int n0, float oscale) {
  __shared__ u16 sA[2][64 * 64];    // 16 KB
  __shared__ u16 sB[2][128 * 64];   // 32 KB
  const int tid = threadIdx.x;
  const int w = tid >> 6, l = tid & 63;
  const int lr = l & 15, lg = l >> 4;
  const int wr = (w >> 1) * 32, wc = (w & 1) * 64;

  f32x4 acc[2][4] = {};

  const int nt = KL >> 6;
  const int lrow = l >> 3;                 // 0..7 within an 8-row group
  const int swz = ((l & 7) ^ lrow) * 8;    // source chunk-XOR (elements)

  auto stage = [&](int buf, int t) {
#pragma unroll
    for (int cq = 0; cq < 2; ++cq) {
      const int r0 = w * 16 + cq * 8;
      gl_lds16(A + (size_t)(m0 + r0 + lrow) * K + t * 64 + swz,
               &sA[buf][r0 * 64]);
    }
#pragma unroll
    for (int cq = 0; cq < 4; ++cq) {
      const int r0 = w * 32 + cq * 8;
      gl_lds16(B + (size_t)(n0 + r0 + lrow) * K + t * 64 + swz,
               &sB[buf][r0 * 64]);
    }
  };

  auto compute = [&](int buf) {
#pragma unroll
    for (int kk = 0; kk < 2; ++kk) {
      const int kc = (((kk << 2) + lg) ^ (lr & 7)) * 8;  // swizzled k-chunk
      bf16x8 af[2], bfr[4];
#pragma unroll
      for (int mf = 0; mf < 2; ++mf)
        af[mf] = *(const bf16x8*)&sA[buf][(wr + mf * 16 + lr) * 64 + kc];
#pragma unroll
      for (int nf = 0; nf < 4; ++nf)
        bfr[nf] = *(const bf16x8*)&sB[buf][(wc + nf * 16 + lr) * 64 + kc];
#pragma unroll
      for (int mf = 0; mf < 2; ++mf)
#pragma unroll
        for (int nf = 0; nf < 4; ++nf)
          acc[mf][nf] = __builtin_amdgcn_mfma_f32_16x16x32_bf16(af[mf], bfr[nf],
                                                                acc[mf][nf], 0, 0, 0);
    }
  };

  stage(0, 0);
  __syncthreads();
  int cur = 0;
  for (int t = 0; t < nt - 1; ++t) {
    stage(cur ^ 1, t + 1);
    compute(cur);
    __syncthreads();
    cur ^= 1;
  }
  compute(cur);

#pragma unroll
  for (int nf = 0; nf < 4; ++nf) {
    const int col = n0 + wc + nf * 16 + lr;
    const float bv = (MODE >= 3) ? 0.0f : bias[col];
#pragma unroll
    for (int mf = 0; mf < 2; ++mf) {
      const int row0 = m0 + wr + mf * 16 + lg * 4;
#pragma unroll
      for (int r = 0; r < 4; ++r) {
        float v = acc[mf][nf][r] + bv;
        if (MODE == 0) v *= oscale;
        if (MODE == 1) v = fmaxf(v, 0.0f);
        const size_t idx = (size_t)(row0 + r) * N + col;
        if (MODE == 3) ((float*)C)[idx] = v;
        else ((u16*)C)[idx] = f2bf(v);
      }
    }
  }
}

// XCD-bijective decode for flattened (64 x-tiles, NY y-panels) grids:
// each XCD owns 8 contiguous x-tiles (A rows L2-resident), x-fast within XCD
// so the active B panel is XCD-resident too. Requires gridDim.x = 64*NY.
DEV void xcd_decode(int id, int& bx, int& by) {
  const int xcd = id & 7;
  const int idx = id >> 3;
  bx = xcd * 8 + (idx & 7);
  by = idx >> 3;
}

// FFN1-style full-K GEMM, 1D swizzled grid (64*NY blocks).
template <int MODE>
__global__ __launch_bounds__(256) void k_gemm64x(const u16* __restrict__ A,
                                                 const u16* __restrict__ B,
                                                 const float* __restrict__ bias,
                                                 void* __restrict__ C, int N, int K) {
  int bx, by;
  xcd_decode(blockIdx.x, bx, by);
  gemm_core64<MODE>(A, B, bias, C, N, K, K, bx * 64, by * 128, 1.0f);
}

// split-K, 1D swizzled grid in x/y, z = K-chunk. partStride in ELEMENTS.
template <int MODE>
__global__ __launch_bounds__(256) void k_gemm64skx(const u16* __restrict__ A,
                                                   const u16* __restrict__ B,
                                                   void* __restrict__ C,
                                                   int N, int K, int Kh,
                                                   size_t partStride) {
  int bx, by;
  xcd_decode(blockIdx.x, bx, by);
  const int z = blockIdx.z;
  char* Cp = (char*)C + (size_t)z * partStride * ((MODE == 3) ? 4 : 2);
  gemm_core64<MODE>(A + z * Kh, B + z * Kh, nullptr, Cp,
                    N, K, Kh, bx * 64, by * 128, 1.0f);
}

__global__ __launch_bounds__(256) void k_gemm_qkv(
    const u16* __restrict__ A, const u16* __restrict__ B0, const u16* __restrict__ B1,
    const u16* __restrict__ B2, const float* __restrict__ c0,
    const float* __restrict__ c1, const float* __restrict__ c2,
    u16* __restrict__ O0, u16* __restrict__ O1, u16* __restrict__ O2) {
  int bx, by;
  xcd_decode(blockIdx.x, bx, by);
  const int z = blockIdx.z;
  const u16* B = (z == 0) ? B0 : (z == 1) ? B1 : B2;
  const float* bias = (z == 0) ? c0 : (z == 1) ? c1 : c2;
  u16* O = (z == 0) ? O0 : (z == 1) ? O1 : O2;
  // Q pre-scaled by log2(e) so attention can run softmax in exp2 domain.
  const float sc = (z == 0) ? 1.44269504f : 1.0f;
  gemm_core64<0>(A, B, bias, O, 1024, 1024, 1024, bx * 64, by * 128, sc);
}

// ---------------- flash attention, kv-split x2, K direct from global -------
// Round-18 change (isolated): K fragments are read straight from global/L1/L2
// (K tile = 8 KB/wave, L2-resident via XCD pinning; all 4 st-chunks of each
// 128B line are consumed so lines are fully used and L1 serves sibling waves).
// This deletes the K LDS round-trip (2 global_load_lds + 8 ds_read_b128 +
// their barrier-coupled waits) from the per-tile critical path. Barrier now
// only orders the reg-staged V^T buffer. LDS 16 KB. Everything else as r17.
__global__ __launch_bounds__(256, 4) void k_attn(const u16* __restrict__ Q,
                                                 const u16* __restrict__ K,
                                                 const u16* __restrict__ V,
                                                 float* __restrict__ pz,
                                                 float* __restrict__ pl) {
  const int id = blockIdx.x;
  const int virt = (id & 7) * 128 + (id >> 3);  // 1024 = 8 XCD * 128
  const int bh = virt >> 5;
  const int qt = (virt >> 1) & 15;
  const int half = virt & 1;
  const int b = bh >> 4, h = bh & 15;
  const int tid = threadIdx.x;
  const int w = tid >> 6, l = tid & 63;
  const int q32 = l & 31, hi = l >> 5;

  __shared__ u16 VT[2][4096];   // V^T tile, chunk-XOR swizzled (16 KB)

  const size_t rb = (size_t)b * 2048;
  const int c0 = h * 64;
  const int q0w = qt * 128 + w * 32;
  const int t0 = half * 16;

  bf16x8 qb[4];
#pragma unroll
  for (int st = 0; st < 4; ++st)
    qb[st] = *(const bf16x8*)(Q + (rb + q0w + q32) * 1024 + c0 + st * 16 + hi * 8);

  f32x16 zacc[2] = {};
  f32x4 lacc = {};

  // per-lane K base: row (rb + kv0 + q32), cols c0 + hi*8 ..
  const u16* Kbase = K + (rb + q32) * 1024 + c0 + hi * 8;

  const int vp = tid & 31, vd0 = (tid >> 5) * 8;
  u16x8 va0, va1;
  auto vload = [&](int t) {
    const u16* v0 = V + (rb + t * 64 + 2 * vp) * 1024 + c0 + vd0;
    va0 = *(const u16x8*)v0;
    va1 = *(const u16x8*)(v0 + 1024);
  };
  auto vstore = [&](int pp) {
    const uint32_t* A0 = (const uint32_t*)&va0;
    const uint32_t* A1 = (const uint32_t*)&va1;
#pragma unroll
    for (int i = 0; i < 8; ++i) {
      const int dh = vd0 + i;
      const int off = ((2 * vp) & 7) + 8 * ((vp >> 2) ^ (dh & 7));
      uint32_t pk = __builtin_amdgcn_perm(A1[i >> 1], A0[i >> 1],
                                          (i & 1) ? 0x07060302u : 0x05040100u);
      *(uint32_t*)&VT[pp][dh * 64 + off] = pk;
    }
  };

  vload(t0);
  vstore(0);
  __syncthreads();

  for (int tt = 0; tt < 16; ++tt) {
    const int bp = tt & 1;
    if (tt + 1 < 16) vload(t0 + tt + 1);  // V latency hides under QK+softmax
    const int kv0 = (t0 + tt) * 64;

    // QK^T swapped, K fragments direct from global (L1/L2-hit)
    f32x16 s[2] = {};
    __builtin_amdgcn_s_setprio(1);
#pragma unroll
    for (int nf = 0; nf < 2; ++nf) {
      const u16* kp = Kbase + (size_t)(kv0 + nf * 32) * 1024;
#pragma unroll
      for (int st = 0; st < 4; ++st) {
        bf16x8 ka = *(const bf16x8*)(kp + st * 16);
        s[nf] = __builtin_amdgcn_mfma_f32_32x32x16_bf16(ka, qb[st], s[nf], 0, 0, 0);
      }
    }
    __builtin_amdgcn_s_setprio(0);

    uint32_t c[16];
#pragma unroll
    for (int nf = 0; nf < 2; ++nf)
#pragma unroll
      for (int m2 = 0; m2 < 8; ++m2) {
        float p0 = __builtin_amdgcn_exp2f(s[nf][2 * m2]);
        float p1 = __builtin_amdgcn_exp2f(s[nf][2 * m2 + 1]);
        lacc[m2 & 3] += p0 + p1;
        uint32_t pk;
        asm("v_cvt_pk_bf16_f32 %0, %1, %2" : "=v"(pk) : "v"(p0), "v"(p1));
        c[nf * 8 + m2] = pk;
      }
#pragma unroll
    for (int ks = 0; ks < 4; ++ks) {
      asm("v_permlane32_swap_b32 %0, %1" : "+v"(c[4 * ks]), "+v"(c[4 * ks + 2]));
      asm("v_permlane32_swap_b32 %0, %1" : "+v"(c[4 * ks + 1]), "+v"(c[4 * ks + 3]));
    }

    if (tt + 1 < 16) vstore(bp ^ 1);

    __builtin_amdgcn_s_setprio(1);
#pragma unroll
    for (int ks = 0; ks < 4; ++ks) {
      union { uint32_t u[4]; bf16x8 v; } pa;
#pragma unroll
      for (int i = 0; i < 4; ++i) pa.u[i] = c[4 * ks + i];
#pragma unroll
      for (int nd = 0; nd < 2; ++nd) {
        bf16x8 vb = *(const bf16x8*)&VT[bp][(nd * 32 + q32) * 64 +
                                            ((ks * 2 + hi) ^ (q32 & 7)) * 8];
        zacc[nd] = __builtin_amdgcn_mfma_f32_32x32x16_bf16(pa.v, vb, zacc[nd], 0, 0, 0);
      }
    }
    __builtin_amdgcn_s_setprio(0);
    __syncthreads();  // all waves done reading VT[bp] before it's rewritten
  }

  float* pzb = pz + (size_t)virt * 8192;
#pragma unroll
  for (int r = 0; r < 16; ++r) {
    const int crow = (r & 3) + 8 * (r >> 2) + 4 * hi;
#pragma unroll
    for (int nd = 0; nd < 2; ++nd)
      pzb[(w * 32 + crow) * 64 + nd * 32 + q32] = zacc[nd][r];
  }
  float lrun = (lacc[0] + lacc[1]) + (lacc[2] + lacc[3]);
  float ltot = lrun + __shfl_xor(lrun, 32, 64);
  if (hi == 0) pl[virt * 128 + w * 32 + q32] = ltot;
}

// merge: z = (zA+zB) * 0.125 / (lA+lB)
__global__ __launch_bounds__(256) void k_attn_merge(const float* __restrict__ pz,
                                                    const float* __restrict__ pl,
                                                    u16* __restrict__ Z) {
  const int id = blockIdx.x;
  const int virt2 = (id & 7) * 64 + (id >> 3);
  const int bh = virt2 >> 4, qt = virt2 & 15;
  const int b = bh >> 4, h = bh & 15;
  const int va = 2 * virt2;
  const int tid = threadIdx.x;
  const int row = tid >> 1;
  const int col0 = (tid & 1) * 32;

  const float la = pl[va * 128 + row];
  const float lb = pl[(va + 1) * 128 + row];
  const float inv = 0.125f / (la + lb);

  const float* za = pz + (size_t)va * 8192 + row * 64 + col0;
  const float* zb = za + 8192;
  u16* zo = Z + ((size_t)b * 2048 + qt * 128 + row) * 1024 + h * 64 + col0;
#pragma unroll
  for (int e = 0; e < 8; ++e) {
    float4 a = *(const float4*)(za + e * 4);
    float4 bv = *(const float4*)(zb + e * 4);
    u16x4 o;
    o[0] = f2bf((a.x + bv.x) * inv);
    o[1] = f2bf((a.y + bv.y) * inv);
    o[2] = f2bf((a.z + bv.z) * inv);
    o[3] = f2bf((a.w + bv.w) * inv);
    *(u16x4*)(zo + e * 4) = o;
  }
}

// ---------------- LayerNorm, fused 2-way bf16-partial merge, bf16-only out -
__global__ __launch_bounds__(256) void k_ln_merge2b(const u16* __restrict__ pp,
                                                    size_t ps,
                                                    const float* __restrict__ bias,
                                                    const float* __restrict__ res,
                                                    const float* __restrict__ g,
                                                    const float* __restrict__ be,
                                                    u16* __restrict__ ob) {
  const int row = blockIdx.x;
  const int tid = threadIdx.x;
  const size_t base = (size_t)row * 1024 + tid * 4;
  float4 rr = *(const float4*)(res + base);
  float4 bv = *(const float4*)(bias + tid * 4);
  float4 v;
  v.x = rr.x + bv.x; v.y = rr.y + bv.y; v.z = rr.z + bv.z; v.w = rr.w + bv.w;
#pragma unroll
  for (int z = 0; z < 2; ++z) {
    u16x4 q = *(const u16x4*)(pp + z * ps + base);
    v.x += b2f(q[0]); v.y += b2f(q[1]); v.z += b2f(q[2]); v.w += b2f(q[3]);
  }

  float s = v.x + v.y + v.z + v.w;
  float s2 = v.x * v.x + v.y * v.y + v.z * v.z + v.w * v.w;
#pragma unroll
  for (int st = 1; st < 64; st <<= 1) {
    s += __shfl_xor(s, st, 64);
    s2 += __shfl_xor(s2, st, 64);
  }
  __shared__ float ps2[8];
  if ((tid & 63) == 0) { ps2[tid >> 6] = s; ps2[4 + (tid >> 6)] = s2; }
  __syncthreads();
  s = ps2[0] + ps2[1] + ps2[2] + ps2[3];
  s2 = ps2[4] + ps2[5] + ps2[6] + ps2[7];
  const float mu = s * 0.0009765625f;
  const float var = s2 * 0.0009765625f - mu * mu;
  const float rs = rsqrtf(var + 1e-5f);
  float4 gg = *(const float4*)(g + tid * 4);
  float4 bb = *(const float4*)(be + tid * 4);
  u16x4 q;
  q[0] = f2bf((v.x - mu) * rs * gg.x + bb.x);
  q[1] = f2bf((v.y - mu) * rs * gg.y + bb.y);
  q[2] = f2bf((v.z - mu) * rs * gg.z + bb.z);
  q[3] = f2bf((v.w - mu) * rs * gg.w + bb.w);
  *(u16x4*)(ob + base) = q;
}

// ---------------- LayerNorm, fused 4-way bf16-partial merge, bf16 residual -
__global__ __launch_bounds__(256) void k_ln_merge4(const u16* __restrict__ pp,
                                                   size_t ps,
                                                   const float* __restrict__ bias,
                                                   const u16* __restrict__ res,
                                                   const float* __restrict__ g,
                                                   const float* __restrict__ be,
                                                   float* __restrict__ of) {
  const int row = blockIdx.x;
  const int tid = threadIdx.x;
  const size_t base = (size_t)row * 1024 + tid * 4;
  u16x4 rq = *(const u16x4*)(res + base);
  float4 bv = *(const float4*)(bias + tid * 4);
  float4 v;
  v.x = b2f(rq[0]) + bv.x; v.y = b2f(rq[1]) + bv.y;
  v.z = b2f(rq[2]) + bv.z; v.w = b2f(rq[3]) + bv.w;
#pragma unroll
  for (int z = 0; z < 4; ++z) {
    u16x4 q = *(const u16x4*)(pp + z * ps + base);
    v.x += b2f(q[0]); v.y += b2f(q[1]); v.z += b2f(q[2]); v.w += b2f(q[3]);
  }

  float s = v.x + v.y + v.z + v.w;
  float s2 = v.x * v.x + v.y * v.y + v.z * v.z + v.w * v.w;
#pragma unroll
  for (int st = 1; st < 64; st <<= 1) {
    s += __shfl_xor(s, st, 64);
    s2 += __shfl_xor(s2, st, 64);
  }
  __shared__ float ps2[8];
  if ((tid & 63) == 0) { ps2[tid >> 6] = s; ps2[4 + (tid >> 6)] = s2; }
  __syncthreads();
  s = ps2[0] + ps2[1] + ps2[2] + ps2[3];
  s2 = ps2[4] + ps2[5] + ps2[6] + ps2[7];
  const float mu = s * 0.0009765625f;
  const float var = s2 * 0.0009765625f - mu * mu;
  const float rs = rsqrtf(var + 1e-5f);
  float4 gg = *(const float4*)(g + tid * 4);
  float4 bb = *(const float4*)(be + tid * 4);
  float4 o;
  o.x = (v.x - mu) * rs * gg.x + bb.x;
  o.y = (v.y - mu) * rs * gg.y + bb.y;
  o.z = (v.z - mu) * rs * gg.z + bb.z;
  o.w = (v.w - mu) * rs * gg.w + bb.w;
  *(float4*)(of + base) = o;
}

// ---------------- launch ----------------
extern "C" void kernel_launch(void* const* d_in, const int* in_sizes, int n_in,
                              void* d_out, int out_size, void* d_ws, size_t ws_size,
                              hipStream_t stream) {
  const float* emb = (const float*)d_in[0];
  const float* Wq  = (const float*)d_in[1];
  const float* bq  = (const float*)d_in[2];
  const float* Wk  = (const float*)d_in[3];
  const float* bk  = (const float*)d_in[4];
  const float* Wv  = (const float*)d_in[5];
  const float* bv  = (const float*)d_in[6];
  const float* W0  = (const float*)d_in[7];
  const float* b0  = (const float*)d_in[8];
  const float* g1  = (const float*)d_in[9];
  const float* be1 = (const float*)d_in[10];
  const float* W1  = (const float*)d_in[11];
  const float* b1  = (const float*)d_in[12];
  const float* W2  = (const float*)d_in[13];
  const float* b2  = (const float*)d_in[14];
  const float* g2  = (const float*)d_in[15];
  const float* be2 = (const float*)d_in[16];

  char* p = (char*)d_ws;
  auto alloc = [&](size_t bytes) { char* r = p; p += bytes; return r; };
  u16* embb = (u16*)alloc(8u << 20);
  u16* Wqb  = (u16*)alloc(2u << 20);
  u16* Wkb  = (u16*)alloc(2u << 20);
  u16* Wvb  = (u16*)alloc(2u << 20);
  u16* W0b  = (u16*)alloc(2u << 20);
  u16* W1b  = (u16*)alloc(8u << 20);
  u16* W2b  = (u16*)alloc(8u << 20);
  u16* Qb   = (u16*)alloc(8u << 20);   // Qb..Zb (32 MB): FFN2 bf16 partials x4
  u16* Kb   = (u16*)alloc(8u << 20);
  u16* Vb   = (u16*)alloc(8u << 20);
  u16* Zb   = (u16*)alloc(8u << 20);
  u16* o1c  = (u16*)alloc(8u << 20);   // out1 (bf16, GEMM input AND residual)
  u16* hb   = (u16*)alloc(32u << 20);  // attn pz(f32) -> W0 partials -> FFN1 out
  float* pl = (float*)alloc(2u << 20);
  (void)Kb; (void)Vb;

  float* pz = (float*)hb;  // 1024 x 8192 f32 = 32 MB

  k_cvt_all<<<2048, 256, 0, stream>>>(emb, Wq, Wk, Wv, W0, W1, W2,
                                      embb, Wqb, Wkb, Wvb, W0b, W1b, W2b);

  k_gemm_qkv<<<dim3(512, 1, 3), 256, 0, stream>>>(embb, Wqb, Wkb, Wvb,
                                                  bq, bk, bv, Qb, Kb, Vb);
  k_attn<<<dim3(1024), 256, 0, stream>>>(Qb, Kb, Vb, pz, pl);
  k_attn_merge<<<dim3(512), 256, 0, stream>>>(pz, pl, Zb);

  // W0-proj split-K x2: bf16 partials into hb (pz consumed).
  u16* w0p = (u16*)hb;
  k_gemm64skx<4><<<dim3(512, 1, 2), 256, 0, stream>>>(Zb, W0b, w0p, 1024, 1024,
                                                      512, (size_t)4096 * 1024);
  // out1 = LN(w0p0 + w0p1 + b0 + emb)  (bf16 only)
  k_ln_merge2b<<<4096, 256, 0, stream>>>(w0p, (size_t)4096 * 1024,
                                         b0, emb, g1, be1, o1c);
  // h = relu(out1 @ W1^T + b1)  (overwrites hb; w0p consumed)
  k_gemm64x<1><<<dim3(2048), 256, 0, stream>>>(o1c, W1b, b1, hb, 4096, 1024);
  // FFN2 split-K x4: bf16 partials into Qb..Zb (dead).
  k_gemm64skx<4><<<dim3(512, 1, 4), 256, 0, stream>>>(hb, W2b, Qb, 1024, 4096,
                                                      1024, (size_t)4096 * 1024);
  // out2 = LN(sum of 4 partials + b2 + out1) -> d_out
  k_ln_merge4<<<4096, 256, 0, stream>>>(Qb, (size_t)4096 * 1024, b2, o1c,
                                        g2, be2, (float*)d_out);
}

// Round 19
// 251.108 us; speedup vs baseline: 1.1134x; 1.1134x over previous
//
#include <hip/hip_runtime.h>
#include <hip/hip_bf16.h>
#include <cstdint>
#include <cmath>

#define DEV __device__ __forceinline__

typedef float f32x4 __attribute__((ext_vector_type(4)));
typedef float f32x16 __attribute__((ext_vector_type(16)));
typedef __bf16 bf16x8 __attribute__((ext_vector_type(8)));
typedef unsigned short u16;
typedef u16 u16x8 __attribute__((ext_vector_type(8)));
typedef u16 u16x4 __attribute__((ext_vector_type(4)));

DEV u16 f2bf(float f) {
  union { float f; uint32_t u; } x{f};
  uint32_t r = x.u + 0x7FFFu + ((x.u >> 16) & 1u);
  return (u16)(r >> 16);
}

DEV float b2f(u16 h) {
  union { uint32_t u; float f; } x{(uint32_t)h << 16};
  return x.f;
}

DEV void gl_lds16(const u16* g, u16* l) {
  __builtin_amdgcn_global_load_lds((const __attribute__((address_space(1))) void*)g,
                                   (__attribute__((address_space(3))) void*)l, 16, 0, 0);
}

// ---------------- fused f32 -> bf16 convert (all 7 tensors, one launch) ----
__global__ __launch_bounds__(256) void k_cvt_all(
    const float* __restrict__ emb, const float* __restrict__ Wq,
    const float* __restrict__ Wk, const float* __restrict__ Wv,
    const float* __restrict__ W0, const float* __restrict__ W1,
    const float* __restrict__ W2,
    u16* __restrict__ embb, u16* __restrict__ Wqb, u16* __restrict__ Wkb,
    u16* __restrict__ Wvb, u16* __restrict__ W0b, u16* __restrict__ W1b,
    u16* __restrict__ W2b) {
  const int step = gridDim.x * blockDim.x;
  for (int i4 = blockIdx.x * blockDim.x + threadIdx.x; i4 < 4194304; i4 += step) {
    const int i = i4 * 4;
    const float* s; u16* d; int off;
    if (i < 4194304)       { s = emb; d = embb; off = 0; }
    else if (i < 5242880)  { s = Wq;  d = Wqb;  off = 4194304; }
    else if (i < 6291456)  { s = Wk;  d = Wkb;  off = 5242880; }
    else if (i < 7340032)  { s = Wv;  d = Wvb;  off = 6291456; }
    else if (i < 8388608)  { s = W0;  d = W0b;  off = 7340032; }
    else if (i < 12582912) { s = W1;  d = W1b;  off = 8388608; }
    else                   { s = W2;  d = W2b;  off = 12582912; }
    float4 v = *reinterpret_cast<const float4*>(s + (i - off));
    u16x4 o;
    o[0] = f2bf(v.x); o[1] = f2bf(v.y); o[2] = f2bf(v.z); o[3] = f2bf(v.w);
    *reinterpret_cast<u16x4*>(d + (i - off)) = o;
  }
}

// ---------------- GEMM core: C[M,N] = A[M,K] @ B[N,K]^T ----------------
// 64x128 tile, 4 waves (2x2 of 32x64), BK=64 -> 16 MFMA per wave per K-step,
// LDS 48 KB, chunk-XOR swizzled on BOTH sides (bank-conflict-free b128 reads).
// MODE 0: bf16 out = (acc+bias)*oscale ; MODE 1: bf16 out = relu(acc+bias)
// MODE 3: f32 out = acc (raw partial) ; MODE 4: bf16 out = acc (raw partial)
template <int MODE>
DEV void gemm_core64(const u16* __restrict__ A, const u16* __restrict__ B,
                     const float* __restrict__ bias,
                     void* __restrict__ C, int N, int K, int KL,
                     int m0, int n0, float oscale) {
  __shared__ u16 sA[2][64 * 64];    // 16 KB
  __shared__ u16 sB[2][128 * 64];   // 32 KB
  const int tid = threadIdx.x;
  const int w = tid >> 6, l = tid & 63;
  const int lr = l & 15, lg = l >> 4;
  const int wr = (w >> 1) * 32, wc = (w & 1) * 64;

  f32x4 acc[2][4] = {};

  const int nt = KL >> 6;
  const int lrow = l >> 3;                 // 0..7 within an 8-row group
  const int swz = ((l & 7) ^ lrow) * 8;    // source chunk-XOR (elements)

  auto stage = [&](int buf, int t) {
#pragma unroll
    for (int cq = 0; cq < 2; ++cq) {
      const int r0 = w * 16 + cq * 8;
      gl_lds16(A + (size_t)(m0 + r0 + lrow) * K + t * 64 + swz,
               &sA[buf][r0 * 64]);
    }
#pragma unroll
    for (int cq = 0; cq < 4; ++cq) {
      const int r0 = w * 32 + cq * 8;
      gl_lds16(B + (size_t)(n0 + r0 + lrow) * K + t * 64 + swz,
               &sB[buf][r0 * 64]);
    }
  };

  auto compute = [&](int buf) {
#pragma unroll
    for (int kk = 0; kk < 2; ++kk) {
      const int kc = (((kk << 2) + lg) ^ (lr & 7)) * 8;  // swizzled k-chunk
      bf16x8 af[2], bfr[4];
#pragma unroll
      for (int mf = 0; mf < 2; ++mf)
        af[mf] = *(const bf16x8*)&sA[buf][(wr + mf * 16 + lr) * 64 + kc];
#pragma unroll
      for (int nf = 0; nf < 4; ++nf)
        bfr[nf] = *(const bf16x8*)&sB[buf][(wc + nf * 16 + lr) * 64 + kc];
#pragma unroll
      for (int mf = 0; mf < 2; ++mf)
#pragma unroll
        for (int nf = 0; nf < 4; ++nf)
          acc[mf][nf] = __builtin_amdgcn_mfma_f32_16x16x32_bf16(af[mf], bfr[nf],
                                                                acc[mf][nf], 0, 0, 0);
    }
  };

  stage(0, 0);
  __syncthreads();
  int cur = 0;
  for (int t = 0; t < nt - 1; ++t) {
    stage(cur ^ 1, t + 1);
    compute(cur);
    __syncthreads();
    cur ^= 1;
  }
  compute(cur);

#pragma unroll
  for (int nf = 0; nf < 4; ++nf) {
    const int col = n0 + wc + nf * 16 + lr;
    const float bv = (MODE >= 3) ? 0.0f : bias[col];
#pragma unroll
    for (int mf = 0; mf < 2; ++mf) {
      const int row0 = m0 + wr + mf * 16 + lg * 4;
#pragma unroll
      for (int r = 0; r < 4; ++r) {
        float v = acc[mf][nf][r] + bv;
        if (MODE == 0) v *= oscale;
        if (MODE == 1) v = fmaxf(v, 0.0f);
        const size_t idx = (size_t)(row0 + r) * N + col;
        if (MODE == 3) ((float*)C)[idx] = v;
        else ((u16*)C)[idx] = f2bf(v);
      }
    }
  }
}

// XCD-bijective decode for flattened (64 x-tiles, NY y-panels) grids:
// each XCD owns 8 contiguous x-tiles (A rows L2-resident), x-fast within XCD
// so the active B panel is XCD-resident too. Requires gridDim.x = 64*NY.
DEV void xcd_decode(int id, int& bx, int& by) {
  const int xcd = id & 7;
  const int idx = id >> 3;
  bx = xcd * 8 + (idx & 7);
  by = idx >> 3;
}

// FFN1-style full-K GEMM, 1D swizzled grid (64*NY blocks).
template <int MODE>
__global__ __launch_bounds__(256) void k_gemm64x(const u16* __restrict__ A,
                                                 const u16* __restrict__ B,
                                                 const float* __restrict__ bias,
                                                 void* __restrict__ C, int N, int K) {
  int bx, by;
  xcd_decode(blockIdx.x, bx, by);
  gemm_core64<MODE>(A, B, bias, C, N, K, K, bx * 64, by * 128, 1.0f);
}

// split-K, 1D swizzled grid in x/y, z = K-chunk. partStride in ELEMENTS.
template <int MODE>
__global__ __launch_bounds__(256) void k_gemm64skx(const u16* __restrict__ A,
                                                   const u16* __restrict__ B,
                                                   void* __restrict__ C,
                                                   int N, int K, int Kh,
                                                   size_t partStride) {
  int bx, by;
  xcd_decode(blockIdx.x, bx, by);
  const int z = blockIdx.z;
  char* Cp = (char*)C + (size_t)z * partStride * ((MODE == 3) ? 4 : 2);
  gemm_core64<MODE>(A + z * Kh, B + z * Kh, nullptr, Cp,
                    N, K, Kh, bx * 64, by * 128, 1.0f);
}

__global__ __launch_bounds__(256) void k_gemm_qkv(
    const u16* __restrict__ A, const u16* __restrict__ B0, const u16* __restrict__ B1,
    const u16* __restrict__ B2, const float* __restrict__ c0,
    const float* __restrict__ c1, const float* __restrict__ c2,
    u16* __restrict__ O0, u16* __restrict__ O1, u16* __restrict__ O2) {
  int bx, by;
  xcd_decode(blockIdx.x, bx, by);
  const int z = blockIdx.z;
  const u16* B = (z == 0) ? B0 : (z == 1) ? B1 : B2;
  const float* bias = (z == 0) ? c0 : (z == 1) ? c1 : c2;
  u16* O = (z == 0) ? O0 : (z == 1) ? O1 : O2;
  // Q pre-scaled by log2(e) so attention can run softmax in exp2 domain.
  const float sc = (z == 0) ? 1.44269504f : 1.0f;
  gemm_core64<0>(A, B, bias, O, 1024, 1024, 1024, bx * 64, by * 128, sc);
}

// ---------------- flash attention, kv-split x2 (round-11/15 proven) --------
// Scores bounded (|s*log2e| < ~40 << 126): P = exp2(s) via raw v_exp_f32,
// exact-sum merge. 1024 blocks (XCD-swizzled): 128 q-rows x 16 kv-tiles,
// independent, 4 blocks/CU. VGPR 64, Occupancy ~36%. K staged via
// global_load_lds with chunk-XOR pre-swizzled source (round-18 showed the
// direct-from-global K gather costs +53%: the LDS round-trip is what converts
// the 32-row K gather into one coalesced load + conflict-free ds_reads).
__global__ __launch_bounds__(256, 4) void k_attn(const u16* __restrict__ Q,
                                                 const u16* __restrict__ K,
                                                 const u16* __restrict__ V,
                                                 float* __restrict__ pz,
                                                 float* __restrict__ pl) {
  const int id = blockIdx.x;
  const int virt = (id & 7) * 128 + (id >> 3);  // 1024 = 8 XCD * 128
  const int bh = virt >> 5;
  const int qt = (virt >> 1) & 15;
  const int half = virt & 1;
  const int b = bh >> 4, h = bh & 15;
  const int tid = threadIdx.x;
  const int w = tid >> 6, l = tid & 63;
  const int q32 = l & 31, hi = l >> 5;

  __shared__ u16 Kl[2][4096];
  __shared__ u16 VT[2][4096];

  const size_t rb = (size_t)b * 2048;
  const int c0 = h * 64;
  const int q0w = qt * 128 + w * 32;
  const int t0 = half * 16;

  bf16x8 qb[4];
#pragma unroll
  for (int st = 0; st < 4; ++st)
    qb[st] = *(const bf16x8*)(Q + (rb + q0w + q32) * 1024 + c0 + st * 16 + hi * 8);

  f32x16 zacc[2] = {};
  f32x4 lacc = {};

  const int skv = w * 16 + (l >> 3);
  const int sc8 = l & 7;
  auto stage_k = [&](int pp, int t) {
#pragma unroll
    for (int cq = 0; cq < 2; ++cq) {
      const int kvl = skv + cq * 8;
      const int dh0 = (sc8 ^ (kvl & 7)) * 8;
      gl_lds16(K + (rb + t * 64 + kvl) * 1024 + c0 + dh0,
               &Kl[pp][w * 1024 + cq * 512]);
    }
  };

  const int vp = tid & 31, vd0 = (tid >> 5) * 8;
  u16x8 va0, va1;
  auto vload = [&](int t) {
    const u16* v0 = V + (rb + t * 64 + 2 * vp) * 1024 + c0 + vd0;
    va0 = *(const u16x8*)v0;
    va1 = *(const u16x8*)(v0 + 1024);
  };
  auto vstore = [&](int pp) {
    const uint32_t* A0 = (const uint32_t*)&va0;
    const uint32_t* A1 = (const uint32_t*)&va1;
#pragma unroll
    for (int i = 0; i < 8; ++i) {
      const int dh = vd0 + i;
      const int off = ((2 * vp) & 7) + 8 * ((vp >> 2) ^ (dh & 7));
      uint32_t pk = __builtin_amdgcn_perm(A1[i >> 1], A0[i >> 1],
                                          (i & 1) ? 0x07060302u : 0x05040100u);
      *(uint32_t*)&VT[pp][dh * 64 + off] = pk;
    }
  };

  stage_k(0, t0);
  vload(t0);
  vstore(0);
  __syncthreads();

  for (int tt = 0; tt < 16; ++tt) {
    const int bp = tt & 1;
    if (tt + 1 < 16) {
      stage_k(bp ^ 1, t0 + tt + 1);
      vload(t0 + tt + 1);
    }
    f32x16 s[2] = {};
    __builtin_amdgcn_s_setprio(1);
#pragma unroll
    for (int nf = 0; nf < 2; ++nf)
#pragma unroll
      for (int st = 0; st < 4; ++st) {
        bf16x8 ka = *(const bf16x8*)&Kl[bp][(nf * 32 + q32) * 64 +
                                            ((st * 2 + hi) ^ (q32 & 7)) * 8];
        s[nf] = __builtin_amdgcn_mfma_f32_32x32x16_bf16(ka, qb[st], s[nf], 0, 0, 0);
      }
    __builtin_amdgcn_s_setprio(0);

    uint32_t c[16];
#pragma unroll
    for (int nf = 0; nf < 2; ++nf)
#pragma unroll
      for (int m2 = 0; m2 < 8; ++m2) {
        float p0 = __builtin_amdgcn_exp2f(s[nf][2 * m2]);
        float p1 = __builtin_amdgcn_exp2f(s[nf][2 * m2 + 1]);
        lacc[m2 & 3] += p0 + p1;
        uint32_t pk;
        asm("v_cvt_pk_bf16_f32 %0, %1, %2" : "=v"(pk) : "v"(p0), "v"(p1));
        c[nf * 8 + m2] = pk;
      }
#pragma unroll
    for (int ks = 0; ks < 4; ++ks) {
      asm("v_permlane32_swap_b32 %0, %1" : "+v"(c[4 * ks]), "+v"(c[4 * ks + 2]));
      asm("v_permlane32_swap_b32 %0, %1" : "+v"(c[4 * ks + 1]), "+v"(c[4 * ks + 3]));
    }

    if (tt + 1 < 16) vstore(bp ^ 1);

    __builtin_amdgcn_s_setprio(1);
#pragma unroll
    for (int ks = 0; ks < 4; ++ks) {
      union { uint32_t u[4]; bf16x8 v; } pa;
#pragma unroll
      for (int i = 0; i < 4; ++i) pa.u[i] = c[4 * ks + i];
#pragma unroll
      for (int nd = 0; nd < 2; ++nd) {
        bf16x8 vb = *(const bf16x8*)&VT[bp][(nd * 32 + q32) * 64 +
                                            ((ks * 2 + hi) ^ (q32 & 7)) * 8];
        zacc[nd] = __builtin_amdgcn_mfma_f32_32x32x16_bf16(pa.v, vb, zacc[nd], 0, 0, 0);
      }
    }
    __builtin_amdgcn_s_setprio(0);
    __syncthreads();
  }

  float* pzb = pz + (size_t)virt * 8192;
#pragma unroll
  for (int r = 0; r < 16; ++r) {
    const int crow = (r & 3) + 8 * (r >> 2) + 4 * hi;
#pragma unroll
    for (int nd = 0; nd < 2; ++nd)
      pzb[(w * 32 + crow) * 64 + nd * 32 + q32] = zacc[nd][r];
  }
  float lrun = (lacc[0] + lacc[1]) + (lacc[2] + lacc[3]);
  float ltot = lrun + __shfl_xor(lrun, 32, 64);
  if (hi == 0) pl[virt * 128 + w * 32 + q32] = ltot;
}

// merge: z = (zA+zB) * 0.125 / (lA+lB)
__global__ __launch_bounds__(256) void k_attn_merge(const float* __restrict__ pz,
                                                    const float* __restrict__ pl,
                                                    u16* __restrict__ Z) {
  const int id = blockIdx.x;
  const int virt2 = (id & 7) * 64 + (id >> 3);
  const int bh = virt2 >> 4, qt = virt2 & 15;
  const int b = bh >> 4, h = bh & 15;
  const int va = 2 * virt2;
  const int tid = threadIdx.x;
  const int row = tid >> 1;
  const int col0 = (tid & 1) * 32;

  const float la = pl[va * 128 + row];
  const float lb = pl[(va + 1) * 128 + row];
  const float inv = 0.125f / (la + lb);

  const float* za = pz + (size_t)va * 8192 + row * 64 + col0;
  const float* zb = za + 8192;
  u16* zo = Z + ((size_t)b * 2048 + qt * 128 + row) * 1024 + h * 64 + col0;
#pragma unroll
  for (int e = 0; e < 8; ++e) {
    float4 a = *(const float4*)(za + e * 4);
    float4 bv = *(const float4*)(zb + e * 4);
    u16x4 o;
    o[0] = f2bf((a.x + bv.x) * inv);
    o[1] = f2bf((a.y + bv.y) * inv);
    o[2] = f2bf((a.z + bv.z) * inv);
    o[3] = f2bf((a.w + bv.w) * inv);
    *(u16x4*)(zo + e * 4) = o;
  }
}

// ---------------- LayerNorm, fused 2-way bf16-partial merge, bf16-only out -
__global__ __launch_bounds__(256) void k_ln_merge2b(const u16* __restrict__ pp,
                                                    size_t ps,
                                                    const float* __restrict__ bias,
                                                    const float* __restrict__ res,
                                                    const float* __restrict__ g,
                                                    const float* __restrict__ be,
                                                    u16* __restrict__ ob) {
  const int row = blockIdx.x;
  const int tid = threadIdx.x;
  const size_t base = (size_t)row * 1024 + tid * 4;
  float4 rr = *(const float4*)(res + base);
  float4 bv = *(const float4*)(bias + tid * 4);
  float4 v;
  v.x = rr.x + bv.x; v.y = rr.y + bv.y; v.z = rr.z + bv.z; v.w = rr.w + bv.w;
#pragma unroll
  for (int z = 0; z < 2; ++z) {
    u16x4 q = *(const u16x4*)(pp + z * ps + base);
    v.x += b2f(q[0]); v.y += b2f(q[1]); v.z += b2f(q[2]); v.w += b2f(q[3]);
  }

  float s = v.x + v.y + v.z + v.w;
  float s2 = v.x * v.x + v.y * v.y + v.z * v.z + v.w * v.w;
#pragma unroll
  for (int st = 1; st < 64; st <<= 1) {
    s += __shfl_xor(s, st, 64);
    s2 += __shfl_xor(s2, st, 64);
  }
  __shared__ float ps2[8];
  if ((tid & 63) == 0) { ps2[tid >> 6] = s; ps2[4 + (tid >> 6)] = s2; }
  __syncthreads();
  s = ps2[0] + ps2[1] + ps2[2] + ps2[3];
  s2 = ps2[4] + ps2[5] + ps2[6] + ps2[7];
  const float mu = s * 0.0009765625f;
  const float var = s2 * 0.0009765625f - mu * mu;
  const float rs = rsqrtf(var + 1e-5f);
  float4 gg = *(const float4*)(g + tid * 4);
  float4 bb = *(const float4*)(be + tid * 4);
  u16x4 q;
  q[0] = f2bf((v.x - mu) * rs * gg.x + bb.x);
  q[1] = f2bf((v.y - mu) * rs * gg.y + bb.y);
  q[2] = f2bf((v.z - mu) * rs * gg.z + bb.z);
  q[3] = f2bf((v.w - mu) * rs * gg.w + bb.w);
  *(u16x4*)(ob + base) = q;
}

// ---------------- LayerNorm, fused 4-way bf16-partial merge, bf16 residual -
__global__ __launch_bounds__(256) void k_ln_merge4(const u16* __restrict__ pp,
                                                   size_t ps,
                                                   const float* __restrict__ bias,
                                                   const u16* __restrict__ res,
                                                   const float* __restrict__ g,
                                                   const float* __restrict__ be,
                                                   float* __restrict__ of) {
  const int row = blockIdx.x;
  const int tid = threadIdx.x;
  const size_t base = (size_t)row * 1024 + tid * 4;
  u16x4 rq = *(const u16x4*)(res + base);
  float4 bv = *(const float4*)(bias + tid * 4);
  float4 v;
  v.x = b2f(rq[0]) + bv.x; v.y = b2f(rq[1]) + bv.y;
  v.z = b2f(rq[2]) + bv.z; v.w = b2f(rq[3]) + bv.w;
#pragma unroll
  for (int z = 0; z < 4; ++z) {
    u16x4 q = *(const u16x4*)(pp + z * ps + base);
    v.x += b2f(q[0]); v.y += b2f(q[1]); v.z += b2f(q[2]); v.w += b2f(q[3]);
  }

  float s = v.x + v.y + v.z + v.w;
  float s2 = v.x * v.x + v.y * v.y + v.z * v.z + v.w * v.w;
#pragma unroll
  for (int st = 1; st < 64; st <<= 1) {
    s += __shfl_xor(s, st, 64);
    s2 += __shfl_xor(s2, st, 64);
  }
  __shared__ float ps2[8];
  if ((tid & 63) == 0) { ps2[tid >> 6] = s; ps2[4 + (tid >> 6)] = s2; }
  __syncthreads();
  s = ps2[0] + ps2[1] + ps2[2] + ps2[3];
  s2 = ps2[4] + ps2[5] + ps2[6] + ps2[7];
  const float mu = s * 0.0009765625f;
  const float var = s2 * 0.0009765625f - mu * mu;
  const float rs = rsqrtf(var + 1e-5f);
  float4 gg = *(const float4*)(g + tid * 4);
  float4 bb = *(const float4*)(be + tid * 4);
  float4 o;
  o.x = (v.x - mu) * rs * gg.x + bb.x;
  o.y = (v.y - mu) * rs * gg.y + bb.y;
  o.z = (v.z - mu) * rs * gg.z + bb.z;
  o.w = (v.w - mu) * rs * gg.w + bb.w;
  *(float4*)(of + base) = o;
}

// ---------------- launch ----------------
extern "C" void kernel_launch(void* const* d_in, const int* in_sizes, int n_in,
                              void* d_out, int out_size, void* d_ws, size_t ws_size,
                              hipStream_t stream) {
  const float* emb = (const float*)d_in[0];
  const float* Wq  = (const float*)d_in[1];
  const float* bq  = (const float*)d_in[2];
  const float* Wk  = (const float*)d_in[3];
  const float* bk  = (const float*)d_in[4];
  const float* Wv  = (const float*)d_in[5];
  const float* bv  = (const float*)d_in[6];
  const float* W0  = (const float*)d_in[7];
  const float* b0  = (const float*)d_in[8];
  const float* g1  = (const float*)d_in[9];
  const float* be1 = (const float*)d_in[10];
  const float* W1  = (const float*)d_in[11];
  const float* b1  = (const float*)d_in[12];
  const float* W2  = (const float*)d_in[13];
  const float* b2  = (const float*)d_in[14];
  const float* g2  = (const float*)d_in[15];
  const float* be2 = (const float*)d_in[16];

  char* p = (char*)d_ws;
  auto alloc = [&](size_t bytes) { char* r = p; p += bytes; return r; };
  u16* embb = (u16*)alloc(8u << 20);
  u16* Wqb  = (u16*)alloc(2u << 20);
  u16* Wkb  = (u16*)alloc(2u << 20);
  u16* Wvb  = (u16*)alloc(2u << 20);
  u16* W0b  = (u16*)alloc(2u << 20);
  u16* W1b  = (u16*)alloc(8u << 20);
  u16* W2b  = (u16*)alloc(8u << 20);
  u16* Qb   = (u16*)alloc(8u << 20);   // Qb..Zb (32 MB): FFN2 bf16 partials x4
  u16* Kb   = (u16*)alloc(8u << 20);
  u16* Vb   = (u16*)alloc(8u << 20);
  u16* Zb   = (u16*)alloc(8u << 20);
  u16* o1c  = (u16*)alloc(8u << 20);   // out1 (bf16, GEMM input AND residual)
  u16* hb   = (u16*)alloc(32u << 20);  // attn pz(f32) -> W0 partials -> FFN1 out
  float* pl = (float*)alloc(2u << 20);
  (void)Kb; (void)Vb;

  float* pz = (float*)hb;  // 1024 x 8192 f32 = 32 MB

  k_cvt_all<<<2048, 256, 0, stream>>>(emb, Wq, Wk, Wv, W0, W1, W2,
                                      embb, Wqb, Wkb, Wvb, W0b, W1b, W2b);

  k_gemm_qkv<<<dim3(512, 1, 3), 256, 0, stream>>>(embb, Wqb, Wkb, Wvb,
                                                  bq, bk, bv, Qb, Kb, Vb);
  k_attn<<<dim3(1024), 256, 0, stream>>>(Qb, Kb, Vb, pz, pl);
  k_attn_merge<<<dim3(512), 256, 0, stream>>>(pz, pl, Zb);

  // W0-proj split-K x2: bf16 partials into hb (pz consumed).
  u16* w0p = (u16*)hb;
  k_gemm64skx<4><<<dim3(512, 1, 2), 256, 0, stream>>>(Zb, W0b, w0p, 1024, 1024,
                                                      512, (size_t)4096 * 1024);
  // out1 = LN(w0p0 + w0p1 + b0 + emb)  (bf16 only)
  k_ln_merge2b<<<4096, 256, 0, stream>>>(w0p, (size_t)4096 * 1024,
                                         b0, emb, g1, be1, o1c);
  // h = relu(out1 @ W1^T + b1)  (overwrites hb; w0p consumed)
  k_gemm64x<1><<<dim3(2048), 256, 0, stream>>>(o1c, W1b, b1, hb, 4096, 1024);
  // FFN2 split-K x4: bf16 partials into Qb..Zb (dead).
  k_gemm64skx<4><<<dim3(512, 1, 4), 256, 0, stream>>>(hb, W2b, Qb, 1024, 4096,
                                                      1024, (size_t)4096 * 1024);
  // out2 = LN(sum of 4 partials + b2 + out1) -> d_out
  k_ln_merge4<<<4096, 256, 0, stream>>>(Qb, (size_t)4096 * 1024, b2, o1c,
                                        g2, be2, (float*)d_out);
}

// Round 20
// 251.098 us; speedup vs baseline: 1.1134x; 1.0000x over previous
//
#include <hip/hip_runtime.h>
#include <hip/hip_bf16.h>
#include <cstdint>
#include <cmath>

#define DEV __device__ __forceinline__

typedef float f32x4 __attribute__((ext_vector_type(4)));
typedef float f32x16 __attribute__((ext_vector_type(16)));
typedef __bf16 bf16x8 __attribute__((ext_vector_type(8)));
typedef unsigned short u16;
typedef u16 u16x8 __attribute__((ext_vector_type(8)));
typedef u16 u16x4 __attribute__((ext_vector_type(4)));

DEV u16 f2bf(float f) {
  union { float f; uint32_t u; } x{f};
  uint32_t r = x.u + 0x7FFFu + ((x.u >> 16) & 1u);
  return (u16)(r >> 16);
}

DEV float b2f(u16 h) {
  union { uint32_t u; float f; } x{(uint32_t)h << 16};
  return x.f;
}

DEV void gl_lds16(const u16* g, u16* l) {
  __builtin_amdgcn_global_load_lds((const __attribute__((address_space(1))) void*)g,
                                   (__attribute__((address_space(3))) void*)l, 16, 0, 0);
}

// ---------------- fused f32 -> bf16 convert (all 7 tensors, one launch) ----
__global__ __launch_bounds__(256) void k_cvt_all(
    const float* __restrict__ emb, const float* __restrict__ Wq,
    const float* __restrict__ Wk, const float* __restrict__ Wv,
    const float* __restrict__ W0, const float* __restrict__ W1,
    const float* __restrict__ W2,
    u16* __restrict__ embb, u16* __restrict__ Wqb, u16* __restrict__ Wkb,
    u16* __restrict__ Wvb, u16* __restrict__ W0b, u16* __restrict__ W1b,
    u16* __restrict__ W2b) {
  const int step = gridDim.x * blockDim.x;
  for (int i4 = blockIdx.x * blockDim.x + threadIdx.x; i4 < 4194304; i4 += step) {
    const int i = i4 * 4;
    const float* s; u16* d; int off;
    if (i < 4194304)       { s = emb; d = embb; off = 0; }
    else if (i < 5242880)  { s = Wq;  d = Wqb;  off = 4194304; }
    else if (i < 6291456)  { s = Wk;  d = Wkb;  off = 5242880; }
    else if (i < 7340032)  { s = Wv;  d = Wvb;  off = 6291456; }
    else if (i < 8388608)  { s = W0;  d = W0b;  off = 7340032; }
    else if (i < 12582912) { s = W1;  d = W1b;  off = 8388608; }
    else                   { s = W2;  d = W2b;  off = 12582912; }
    float4 v = *reinterpret_cast<const float4*>(s + (i - off));
    u16x4 o;
    o[0] = f2bf(v.x); o[1] = f2bf(v.y); o[2] = f2bf(v.z); o[3] = f2bf(v.w);
    *reinterpret_cast<u16x4*>(d + (i - off)) = o;
  }
}

// ---------------- GEMM core: C[M,N] = A[M,K] @ B[N,K]^T ----------------
// 64x128 tile, 4 waves (2x2 of 32x64), BK=64 -> 16 MFMA per wave per K-step,
// LDS 48 KB, chunk-XOR swizzled on BOTH sides (bank-conflict-free b128 reads).
// MODE 0: bf16 out = (acc+bias)*oscale ; MODE 1: bf16 out = relu(acc+bias)
// MODE 3: f32 out = acc (raw partial) ; MODE 4: bf16 out = acc (raw partial)
template <int MODE>
DEV void gemm_core64(const u16* __restrict__ A, const u16* __restrict__ B,
                     const float* __restrict__ bias,
                     void* __restrict__ C, int N, int K, int KL,
                     int m0, int n0, float oscale) {
  __shared__ u16 sA[2][64 * 64];    // 16 KB
  __shared__ u16 sB[2][128 * 64];   // 32 KB
  const int tid = threadIdx.x;
  const int w = tid >> 6, l = tid & 63;
  const int lr = l & 15, lg = l >> 4;
  const int wr = (w >> 1) * 32, wc = (w & 1) * 64;

  f32x4 acc[2][4] = {};

  const int nt = KL >> 6;
  const int lrow = l >> 3;                 // 0..7 within an 8-row group
  const int swz = ((l & 7) ^ lrow) * 8;    // source chunk-XOR (elements)

  auto stage = [&](int buf, int t) {
#pragma unroll
    for (int cq = 0; cq < 2; ++cq) {
      const int r0 = w * 16 + cq * 8;
      gl_lds16(A + (size_t)(m0 + r0 + lrow) * K + t * 64 + swz,
               &sA[buf][r0 * 64]);
    }
#pragma unroll
    for (int cq = 0; cq < 4; ++cq) {
      const int r0 = w * 32 + cq * 8;
      gl_lds16(B + (size_t)(n0 + r0 + lrow) * K + t * 64 + swz,
               &sB[buf][r0 * 64]);
    }
  };

  auto compute = [&](int buf) {
#pragma unroll
    for (int kk = 0; kk < 2; ++kk) {
      const int kc = (((kk << 2) + lg) ^ (lr & 7)) * 8;  // swizzled k-chunk
      bf16x8 af[2], bfr[4];
#pragma unroll
      for (int mf = 0; mf < 2; ++mf)
        af[mf] = *(const bf16x8*)&sA[buf][(wr + mf * 16 + lr) * 64 + kc];
#pragma unroll
      for (int nf = 0; nf < 4; ++nf)
        bfr[nf] = *(const bf16x8*)&sB[buf][(wc + nf * 16 + lr) * 64 + kc];
#pragma unroll
      for (int mf = 0; mf < 2; ++mf)
#pragma unroll
        for (int nf = 0; nf < 4; ++nf)
          acc[mf][nf] = __builtin_amdgcn_mfma_f32_16x16x32_bf16(af[mf], bfr[nf],
                                                                acc[mf][nf], 0, 0, 0);
    }
  };

  stage(0, 0);
  __syncthreads();
  int cur = 0;
  for (int t = 0; t < nt - 1; ++t) {
    stage(cur ^ 1, t + 1);
    compute(cur);
    __syncthreads();
    cur ^= 1;
  }
  compute(cur);

#pragma unroll
  for (int nf = 0; nf < 4; ++nf) {
    const int col = n0 + wc + nf * 16 + lr;
    const float bv = (MODE >= 3) ? 0.0f : bias[col];
#pragma unroll
    for (int mf = 0; mf < 2; ++mf) {
      const int row0 = m0 + wr + mf * 16 + lg * 4;
#pragma unroll
      for (int r = 0; r < 4; ++r) {
        float v = acc[mf][nf][r] + bv;
        if (MODE == 0) v *= oscale;
        if (MODE == 1) v = fmaxf(v, 0.0f);
        const size_t idx = (size_t)(row0 + r) * N + col;
        if (MODE == 3) ((float*)C)[idx] = v;
        else ((u16*)C)[idx] = f2bf(v);
      }
    }
  }
}

// XCD-bijective decode for flattened (64 x-tiles, NY y-panels) grids:
// each XCD owns 8 contiguous x-tiles (A rows L2-resident), x-fast within XCD
// so the active B panel is XCD-resident too. Requires gridDim.x = 64*NY.
DEV void xcd_decode(int id, int& bx, int& by) {
  const int xcd = id & 7;
  const int idx = id >> 3;
  bx = xcd * 8 + (idx & 7);
  by = idx >> 3;
}

// FFN1-style full-K GEMM, 1D swizzled grid (64*NY blocks).
template <int MODE>
__global__ __launch_bounds__(256) void k_gemm64x(const u16* __restrict__ A,
                                                 const u16* __restrict__ B,
                                                 const float* __restrict__ bias,
                                                 void* __restrict__ C, int N, int K) {
  int bx, by;
  xcd_decode(blockIdx.x, bx, by);
  gemm_core64<MODE>(A, B, bias, C, N, K, K, bx * 64, by * 128, 1.0f);
}

// split-K, 1D swizzled grid in x/y, z = K-chunk. partStride in ELEMENTS.
template <int MODE>
__global__ __launch_bounds__(256) void k_gemm64skx(const u16* __restrict__ A,
                                                   const u16* __restrict__ B,
                                                   void* __restrict__ C,
                                                   int N, int K, int Kh,
                                                   size_t partStride) {
  int bx, by;
  xcd_decode(blockIdx.x, bx, by);
  const int z = blockIdx.z;
  char* Cp = (char*)C + (size_t)z * partStride * ((MODE == 3) ? 4 : 2);
  gemm_core64<MODE>(A + z * Kh, B + z * Kh, nullptr, Cp,
                    N, K, Kh, bx * 64, by * 128, 1.0f);
}

__global__ __launch_bounds__(256) void k_gemm_qkv(
    const u16* __restrict__ A, const u16* __restrict__ B0, const u16* __restrict__ B1,
    const u16* __restrict__ B2, const float* __restrict__ c0,
    const float* __restrict__ c1, const float* __restrict__ c2,
    u16* __restrict__ O0, u16* __restrict__ O1, u16* __restrict__ O2) {
  int bx, by;
  xcd_decode(blockIdx.x, bx, by);
  const int z = blockIdx.z;
  const u16* B = (z == 0) ? B0 : (z == 1) ? B1 : B2;
  const float* bias = (z == 0) ? c0 : (z == 1) ? c1 : c2;
  u16* O = (z == 0) ? O0 : (z == 1) ? O1 : O2;
  // Q pre-scaled by log2(e) so attention can run softmax in exp2 domain.
  const float sc = (z == 0) ? 1.44269504f : 1.0f;
  gemm_core64<0>(A, B, bias, O, 1024, 1024, 1024, bx * 64, by * 128, sc);
}

// ---------------- flash attention, kv-split x2, bf16 partials --------------
// Scores bounded (|s*log2e| < ~40 << 126): P = exp2(s) via raw v_exp_f32,
// exact-sum merge. 1024 blocks (XCD-swizzled): 128 q-rows x 16 kv-tiles,
// independent, 4 blocks/CU. VGPR 64, Occupancy ~36%. K staged via
// global_load_lds with chunk-XOR pre-swizzled source (round-18 showed the
// direct-from-global K gather costs +53%). Round-20: partials in bf16
// (proven at absmax 0.031 in rounds 13-14) -> merge traffic halves.
__global__ __launch_bounds__(256, 4) void k_attn(const u16* __restrict__ Q,
                                                 const u16* __restrict__ K,
                                                 const u16* __restrict__ V,
                                                 u16* __restrict__ pz,
                                                 float* __restrict__ pl) {
  const int id = blockIdx.x;
  const int virt = (id & 7) * 128 + (id >> 3);  // 1024 = 8 XCD * 128
  const int bh = virt >> 5;
  const int qt = (virt >> 1) & 15;
  const int half = virt & 1;
  const int b = bh >> 4, h = bh & 15;
  const int tid = threadIdx.x;
  const int w = tid >> 6, l = tid & 63;
  const int q32 = l & 31, hi = l >> 5;

  __shared__ u16 Kl[2][4096];
  __shared__ u16 VT[2][4096];

  const size_t rb = (size_t)b * 2048;
  const int c0 = h * 64;
  const int q0w = qt * 128 + w * 32;
  const int t0 = half * 16;

  bf16x8 qb[4];
#pragma unroll
  for (int st = 0; st < 4; ++st)
    qb[st] = *(const bf16x8*)(Q + (rb + q0w + q32) * 1024 + c0 + st * 16 + hi * 8);

  f32x16 zacc[2] = {};
  f32x4 lacc = {};

  const int skv = w * 16 + (l >> 3);
  const int sc8 = l & 7;
  auto stage_k = [&](int pp, int t) {
#pragma unroll
    for (int cq = 0; cq < 2; ++cq) {
      const int kvl = skv + cq * 8;
      const int dh0 = (sc8 ^ (kvl & 7)) * 8;
      gl_lds16(K + (rb + t * 64 + kvl) * 1024 + c0 + dh0,
               &Kl[pp][w * 1024 + cq * 512]);
    }
  };

  const int vp = tid & 31, vd0 = (tid >> 5) * 8;
  u16x8 va0, va1;
  auto vload = [&](int t) {
    const u16* v0 = V + (rb + t * 64 + 2 * vp) * 1024 + c0 + vd0;
    va0 = *(const u16x8*)v0;
    va1 = *(const u16x8*)(v0 + 1024);
  };
  auto vstore = [&](int pp) {
    const uint32_t* A0 = (const uint32_t*)&va0;
    const uint32_t* A1 = (const uint32_t*)&va1;
#pragma unroll
    for (int i = 0; i < 8; ++i) {
      const int dh = vd0 + i;
      const int off = ((2 * vp) & 7) + 8 * ((vp >> 2) ^ (dh & 7));
      uint32_t pk = __builtin_amdgcn_perm(A1[i >> 1], A0[i >> 1],
                                          (i & 1) ? 0x07060302u : 0x05040100u);
      *(uint32_t*)&VT[pp][dh * 64 + off] = pk;
    }
  };

  stage_k(0, t0);
  vload(t0);
  vstore(0);
  __syncthreads();

  for (int tt = 0; tt < 16; ++tt) {
    const int bp = tt & 1;
    if (tt + 1 < 16) {
      stage_k(bp ^ 1, t0 + tt + 1);
      vload(t0 + tt + 1);
    }
    f32x16 s[2] = {};
    __builtin_amdgcn_s_setprio(1);
#pragma unroll
    for (int nf = 0; nf < 2; ++nf)
#pragma unroll
      for (int st = 0; st < 4; ++st) {
        bf16x8 ka = *(const bf16x8*)&Kl[bp][(nf * 32 + q32) * 64 +
                                            ((st * 2 + hi) ^ (q32 & 7)) * 8];
        s[nf] = __builtin_amdgcn_mfma_f32_32x32x16_bf16(ka, qb[st], s[nf], 0, 0, 0);
      }
    __builtin_amdgcn_s_setprio(0);

    uint32_t c[16];
#pragma unroll
    for (int nf = 0; nf < 2; ++nf)
#pragma unroll
      for (int m2 = 0; m2 < 8; ++m2) {
        float p0 = __builtin_amdgcn_exp2f(s[nf][2 * m2]);
        float p1 = __builtin_amdgcn_exp2f(s[nf][2 * m2 + 1]);
        lacc[m2 & 3] += p0 + p1;
        uint32_t pk;
        asm("v_cvt_pk_bf16_f32 %0, %1, %2" : "=v"(pk) : "v"(p0), "v"(p1));
        c[nf * 8 + m2] = pk;
      }
#pragma unroll
    for (int ks = 0; ks < 4; ++ks) {
      asm("v_permlane32_swap_b32 %0, %1" : "+v"(c[4 * ks]), "+v"(c[4 * ks + 2]));
      asm("v_permlane32_swap_b32 %0, %1" : "+v"(c[4 * ks + 1]), "+v"(c[4 * ks + 3]));
    }

    if (tt + 1 < 16) vstore(bp ^ 1);

    __builtin_amdgcn_s_setprio(1);
#pragma unroll
    for (int ks = 0; ks < 4; ++ks) {
      union { uint32_t u[4]; bf16x8 v; } pa;
#pragma unroll
      for (int i = 0; i < 4; ++i) pa.u[i] = c[4 * ks + i];
#pragma unroll
      for (int nd = 0; nd < 2; ++nd) {
        bf16x8 vb = *(const bf16x8*)&VT[bp][(nd * 32 + q32) * 64 +
                                            ((ks * 2 + hi) ^ (q32 & 7)) * 8];
        zacc[nd] = __builtin_amdgcn_mfma_f32_32x32x16_bf16(pa.v, vb, zacc[nd], 0, 0, 0);
      }
    }
    __builtin_amdgcn_s_setprio(0);
    __syncthreads();
  }

  // bf16 partials: pz[virt][row 0..127][dh 0..63]
  u16* pzb = pz + (size_t)virt * 8192;
#pragma unroll
  for (int r = 0; r < 16; ++r) {
    const int crow = (r & 3) + 8 * (r >> 2) + 4 * hi;
#pragma unroll
    for (int nd = 0; nd < 2; ++nd)
      pzb[(w * 32 + crow) * 64 + nd * 32 + q32] = f2bf(zacc[nd][r]);
  }
  float lrun = (lacc[0] + lacc[1]) + (lacc[2] + lacc[3]);
  float ltot = lrun + __shfl_xor(lrun, 32, 64);
  if (hi == 0) pl[virt * 128 + w * 32 + q32] = ltot;
}

// merge: z = (zA+zB) * 0.125 / (lA+lB)  (bf16 partials)
__global__ __launch_bounds__(256) void k_attn_merge(const u16* __restrict__ pz,
                                                    const float* __restrict__ pl,
                                                    u16* __restrict__ Z) {
  const int id = blockIdx.x;
  const int virt2 = (id & 7) * 64 + (id >> 3);
  const int bh = virt2 >> 4, qt = virt2 & 15;
  const int b = bh >> 4, h = bh & 15;
  const int va = 2 * virt2;
  const int tid = threadIdx.x;
  const int row = tid >> 1;
  const int col0 = (tid & 1) * 32;

  const float la = pl[va * 128 + row];
  const float lb = pl[(va + 1) * 128 + row];
  const float inv = 0.125f / (la + lb);

  const u16* za = pz + (size_t)va * 8192 + row * 64 + col0;
  const u16* zb = za + 8192;
  u16* zo = Z + ((size_t)b * 2048 + qt * 128 + row) * 1024 + h * 64 + col0;
#pragma unroll
  for (int e = 0; e < 8; ++e) {
    u16x4 a = *(const u16x4*)(za + e * 4);
    u16x4 bq = *(const u16x4*)(zb + e * 4);
    u16x4 o;
    o[0] = f2bf((b2f(a[0]) + b2f(bq[0])) * inv);
    o[1] = f2bf((b2f(a[1]) + b2f(bq[1])) * inv);
    o[2] = f2bf((b2f(a[2]) + b2f(bq[2])) * inv);
    o[3] = f2bf((b2f(a[3]) + b2f(bq[3])) * inv);
    *(u16x4*)(zo + e * 4) = o;
  }
}

// ---------------- LayerNorm, fused 2-way bf16-partial merge, bf16-only out -
__global__ __launch_bounds__(256) void k_ln_merge2b(const u16* __restrict__ pp,
                                                    size_t ps,
                                                    const float* __restrict__ bias,
                                                    const float* __restrict__ res,
                                                    const float* __restrict__ g,
                                                    const float* __restrict__ be,
                                                    u16* __restrict__ ob) {
  const int row = blockIdx.x;
  const int tid = threadIdx.x;
  const size_t base = (size_t)row * 1024 + tid * 4;
  float4 rr = *(const float4*)(res + base);
  float4 bv = *(const float4*)(bias + tid * 4);
  float4 v;
  v.x = rr.x + bv.x; v.y = rr.y + bv.y; v.z = rr.z + bv.z; v.w = rr.w + bv.w;
#pragma unroll
  for (int z = 0; z < 2; ++z) {
    u16x4 q = *(const u16x4*)(pp + z * ps + base);
    v.x += b2f(q[0]); v.y += b2f(q[1]); v.z += b2f(q[2]); v.w += b2f(q[3]);
  }

  float s = v.x + v.y + v.z + v.w;
  float s2 = v.x * v.x + v.y * v.y + v.z * v.z + v.w * v.w;
#pragma unroll
  for (int st = 1; st < 64; st <<= 1) {
    s += __shfl_xor(s, st, 64);
    s2 += __shfl_xor(s2, st, 64);
  }
  __shared__ float ps2[8];
  if ((tid & 63) == 0) { ps2[tid >> 6] = s; ps2[4 + (tid >> 6)] = s2; }
  __syncthreads();
  s = ps2[0] + ps2[1] + ps2[2] + ps2[3];
  s2 = ps2[4] + ps2[5] + ps2[6] + ps2[7];
  const float mu = s * 0.0009765625f;
  const float var = s2 * 0.0009765625f - mu * mu;
  const float rs = rsqrtf(var + 1e-5f);
  float4 gg = *(const float4*)(g + tid * 4);
  float4 bb = *(const float4*)(be + tid * 4);
  u16x4 q;
  q[0] = f2bf((v.x - mu) * rs * gg.x + bb.x);
  q[1] = f2bf((v.y - mu) * rs * gg.y + bb.y);
  q[2] = f2bf((v.z - mu) * rs * gg.z + bb.z);
  q[3] = f2bf((v.w - mu) * rs * gg.w + bb.w);
  *(u16x4*)(ob + base) = q;
}

// ---------------- LayerNorm, fused 4-way bf16-partial merge, bf16 residual -
__global__ __launch_bounds__(256) void k_ln_merge4(const u16* __restrict__ pp,
                                                   size_t ps,
                                                   const float* __restrict__ bias,
                                                   const u16* __restrict__ res,
                                                   const float* __restrict__ g,
                                                   const float* __restrict__ be,
                                                   float* __restrict__ of) {
  const int row = blockIdx.x;
  const int tid = threadIdx.x;
  const size_t base = (size_t)row * 1024 + tid * 4;
  u16x4 rq = *(const u16x4*)(res + base);
  float4 bv = *(const float4*)(bias + tid * 4);
  float4 v;
  v.x = b2f(rq[0]) + bv.x; v.y = b2f(rq[1]) + bv.y;
  v.z = b2f(rq[2]) + bv.z; v.w = b2f(rq[3]) + bv.w;
#pragma unroll
  for (int z = 0; z < 4; ++z) {
    u16x4 q = *(const u16x4*)(pp + z * ps + base);
    v.x += b2f(q[0]); v.y += b2f(q[1]); v.z += b2f(q[2]); v.w += b2f(q[3]);
  }

  float s = v.x + v.y + v.z + v.w;
  float s2 = v.x * v.x + v.y * v.y + v.z * v.z + v.w * v.w;
#pragma unroll
  for (int st = 1; st < 64; st <<= 1) {
    s += __shfl_xor(s, st, 64);
    s2 += __shfl_xor(s2, st, 64);
  }
  __shared__ float ps2[8];
  if ((tid & 63) == 0) { ps2[tid >> 6] = s; ps2[4 + (tid >> 6)] = s2; }
  __syncthreads();
  s = ps2[0] + ps2[1] + ps2[2] + ps2[3];
  s2 = ps2[4] + ps2[5] + ps2[6] + ps2[7];
  const float mu = s * 0.0009765625f;
  const float var = s2 * 0.0009765625f - mu * mu;
  const float rs = rsqrtf(var + 1e-5f);
  float4 gg = *(const float4*)(g + tid * 4);
  float4 bb = *(const float4*)(be + tid * 4);
  float4 o;
  o.x = (v.x - mu) * rs * gg.x + bb.x;
  o.y = (v.y - mu) * rs * gg.y + bb.y;
  o.z = (v.z - mu) * rs * gg.z + bb.z;
  o.w = (v.w - mu) * rs * gg.w + bb.w;
  *(float4*)(of + base) = o;
}

// ---------------- launch ----------------
extern "C" void kernel_launch(void* const* d_in, const int* in_sizes, int n_in,
                              void* d_out, int out_size, void* d_ws, size_t ws_size,
                              hipStream_t stream) {
  const float* emb = (const float*)d_in[0];
  const float* Wq  = (const float*)d_in[1];
  const float* bq  = (const float*)d_in[2];
  const float* Wk  = (const float*)d_in[3];
  const float* bk  = (const float*)d_in[4];
  const float* Wv  = (const float*)d_in[5];
  const float* bv  = (const float*)d_in[6];
  const float* W0  = (const float*)d_in[7];
  const float* b0  = (const float*)d_in[8];
  const float* g1  = (const float*)d_in[9];
  const float* be1 = (const float*)d_in[10];
  const float* W1  = (const float*)d_in[11];
  const float* b1  = (const float*)d_in[12];
  const float* W2  = (const float*)d_in[13];
  const float* b2  = (const float*)d_in[14];
  const float* g2  = (const float*)d_in[15];
  const float* be2 = (const float*)d_in[16];

  char* p = (char*)d_ws;
  auto alloc = [&](size_t bytes) { char* r = p; p += bytes; return r; };
  u16* embb = (u16*)alloc(8u << 20);
  u16* Wqb  = (u16*)alloc(2u << 20);
  u16* Wkb  = (u16*)alloc(2u << 20);
  u16* Wvb  = (u16*)alloc(2u << 20);
  u16* W0b  = (u16*)alloc(2u << 20);
  u16* W1b  = (u16*)alloc(8u << 20);
  u16* W2b  = (u16*)alloc(8u << 20);
  u16* Qb   = (u16*)alloc(8u << 20);   // Qb..Zb (32 MB): FFN2 bf16 partials x4
  u16* Kb   = (u16*)alloc(8u << 20);
  u16* Vb   = (u16*)alloc(8u << 20);
  u16* Zb   = (u16*)alloc(8u << 20);
  u16* o1c  = (u16*)alloc(8u << 20);   // out1 (bf16, GEMM input AND residual)
  u16* hb   = (u16*)alloc(32u << 20);  // attn pz(bf16) -> W0 partials -> FFN1 out
  float* pl = (float*)alloc(2u << 20);
  (void)Kb; (void)Vb;

  u16* pz = (u16*)hb;  // 1024 x 8192 bf16 = 16 MB (within hb)

  k_cvt_all<<<2048, 256, 0, stream>>>(emb, Wq, Wk, Wv, W0, W1, W2,
                                      embb, Wqb, Wkb, Wvb, W0b, W1b, W2b);

  k_gemm_qkv<<<dim3(512, 1, 3), 256, 0, stream>>>(embb, Wqb, Wkb, Wvb,
                                                  bq, bk, bv, Qb, Kb, Vb);
  k_attn<<<dim3(1024), 256, 0, stream>>>(Qb, Kb, Vb, pz, pl);
  k_attn_merge<<<dim3(512), 256, 0, stream>>>(pz, pl, Zb);

  // W0-proj split-K x2: bf16 partials into hb (pz consumed).
  u16* w0p = (u16*)hb;
  k_gemm64skx<4><<<dim3(512, 1, 2), 256, 0, stream>>>(Zb, W0b, w0p, 1024, 1024,
                                                      512, (size_t)4096 * 1024);
  // out1 = LN(w0p0 + w0p1 + b0 + emb)  (bf16 only)
  k_ln_merge2b<<<4096, 256, 0, stream>>>(w0p, (size_t)4096 * 1024,
                                         b0, emb, g1, be1, o1c);
  // h = relu(out1 @ W1^T + b1)  (overwrites hb; w0p consumed)
  k_gemm64x<1><<<dim3(2048), 256, 0, stream>>>(o1c, W1b, b1, hb, 4096, 1024);
  // FFN2 split-K x4: bf16 partials into Qb..Zb (dead).
  k_gemm64skx<4><<<dim3(512, 1, 4), 256, 0, stream>>>(hb, W2b, Qb, 1024, 4096,
                                                      1024, (size_t)4096 * 1024);
  // out2 = LN(sum of 4 partials + b2 + out1) -> d_out
  k_ln_merge4<<<4096, 256, 0, stream>>>(Qb, (size_t)4096 * 1024, b2, o1c,
                                        g2, be2, (float*)d_out);
}